// Round 5
// baseline (12802.930 us; speedup 1.0000x reference)
//
#include <hip/hip_runtime.h>
#include <cstdint>

#define DD 64
#define HH 2
#define LAY 3
#define NN 50000
#define GG 128
#define EE 600000
#define NEE 300000
#define NAUG (NN + GG)            // 50128
#define E2 (EE + 2 * NN)          // 700000: loop edges start here
#define ESZ (E2 + NAUG)           // 750128
#define EPS_GEN_F 1e-7f
#define EPS_LN_F 1e-5f
#define SCAN_B 1024
#define NBLK ((NAUG + SCAN_B - 1) / SCAN_B)  // 49

// ---------------- device helpers ----------------

__device__ __forceinline__ float2 ld2(const float* p) {
  return *reinterpret_cast<const float2*>(p);
}
__device__ __forceinline__ float4 ld4(const float* p) {
  return *reinterpret_cast<const float4*>(p);
}
__device__ __forceinline__ void st2(float* p, float x, float y) {
  *reinterpret_cast<float2*>(p) = make_float2(x, y);
}

// butterfly sum within each 32-lane half (xor offsets never cross bit 5)
__device__ __forceinline__ float half_sum(float v) {
#pragma unroll
  for (int off = 16; off; off >>= 1) v += __shfl_xor(v, off);
  return v;  // identical on all lanes of the half
}

// e_aug[e][2*hl .. 2*hl+1] without materializing e_aug (hl in [0,32))
__device__ __forceinline__ float2 ea2_val(int e, int hl, const float* __restrict__ ea,
                                          const float* __restrict__ la) {
  if (e < EE) return ld2(ea + (size_t)e * DD + 2 * hl);
  if (e < E2) return make_float2((hl == 0) ? 1.0f : 0.0f, 0.0f);  // e_p rows
  return ld2(la + (size_t)(e - E2) * DD + 2 * hl);                // loop_attr rows
}

__device__ __forceinline__ int dst_of(int e, const int* __restrict__ ei1,
                                      const int* __restrict__ batch) {
  if (e < EE) return ei1[e];
  if (e < EE + NN) return batch[e - EE] + NN;  // u -> v
  if (e < E2) return e - (EE + NN);            // v -> u
  return e - E2;                               // loop
}
__device__ __forceinline__ int src_of(int e, const int* __restrict__ ei0,
                                      const int* __restrict__ batch) {
  if (e < EE) return ei0[e];
  if (e < EE + NN) return e - EE;
  if (e < E2) return batch[e - (EE + NN)] + NN;
  return e - E2;
}

// ---------------- CSR build ----------------

__global__ void hist_k(const int* __restrict__ ei1, const int* __restrict__ batch,
                       int* __restrict__ deg) {
  for (int e = blockIdx.x * blockDim.x + threadIdx.x; e < ESZ; e += gridDim.x * blockDim.x)
    atomicAdd(&deg[dst_of(e, ei1, batch)], 1);
}

__global__ __launch_bounds__(SCAN_B) void scan1_k(const int* __restrict__ deg,
                                                  int* __restrict__ rowst,
                                                  int* __restrict__ bsum) {
  __shared__ int buf[SCAN_B];
  int i = blockIdx.x * SCAN_B + threadIdx.x;
  int v = (i < NAUG) ? deg[i] : 0;
  buf[threadIdx.x] = v;
  __syncthreads();
  int acc = v;
#pragma unroll
  for (int off = 1; off < SCAN_B; off <<= 1) {
    int t = (threadIdx.x >= off) ? buf[threadIdx.x - off] : 0;
    __syncthreads();
    buf[threadIdx.x] = acc = acc + t;
    __syncthreads();
  }
  if (i < NAUG) rowst[i] = acc - v;  // block-local exclusive
  if (threadIdx.x == SCAN_B - 1) bsum[blockIdx.x] = acc;
}

__global__ void scan2_k(const int* __restrict__ bsum, int* __restrict__ bpre,
                        int* __restrict__ rowst) {
  if (threadIdx.x == 0) {
    int run = 0;
    for (int b = 0; b < NBLK; b++) {
      bpre[b] = run;
      run += bsum[b];
    }
    rowst[NAUG] = run;  // == ESZ
  }
}

__global__ void scan3_k(int* __restrict__ rowst, const int* __restrict__ bpre) {
  int i = blockIdx.x * blockDim.x + threadIdx.x;
  if (i < NAUG) rowst[i] += bpre[i / SCAN_B];
}

__global__ void scatter_k(const int* __restrict__ ei0, const int* __restrict__ ei1,
                          const int* __restrict__ batch, const int* __restrict__ rowst,
                          int* __restrict__ fill, int* __restrict__ ceid,
                          int* __restrict__ csrc) {
  for (int e = blockIdx.x * blockDim.x + threadIdx.x; e < ESZ; e += gridDim.x * blockDim.x) {
    int dn = dst_of(e, ei1, batch);
    int pos = rowst[dn] + atomicAdd(&fill[dn], 1);
    ceid[pos] = e;
    csrc[pos] = src_of(e, ei0, batch);
  }
}

// graph start offsets from sorted batch
__global__ void gs_k(const int* __restrict__ batch, int* __restrict__ gs) {
  int i = blockIdx.x * blockDim.x + threadIdx.x;
  if (i >= NN) return;
  int b = batch[i];
  int prev = (i > 0) ? batch[i - 1] : -1;
  for (int g = prev + 1; g <= b; ++g) gs[g] = i;
  if (i == NN - 1)
    for (int g = b + 1; g <= GG; ++g) gs[g] = NN;
}

__global__ void hinit_k(const float4* __restrict__ x, const float4* __restrict__ cond,
                        float4* __restrict__ h) {
  for (int idx = blockIdx.x * blockDim.x + threadIdx.x; idx < NAUG * 16;
       idx += gridDim.x * blockDim.x)
    h[idx] = (idx < NN * 16) ? x[idx] : cond[idx - NN * 16];
}

// loop_attr for u-nodes: avg of non-loop in-edge attrs (2 edges/wave, one per half)
__global__ __launch_bounds__(256) void loopattr_u_k(const float* __restrict__ eattr,
                                                    const int* __restrict__ rowst,
                                                    const int* __restrict__ ceid,
                                                    float* __restrict__ la) {
  const int lane = threadIdx.x & 63;
  const int half = lane >> 5, hl = lane & 31;
  const int wv = threadIdx.x >> 6;
  for (int i = blockIdx.x * 4 + wv; i < NN; i += gridDim.x * 4) {
    int rs = rowst[i], re = rowst[i + 1];
    float ax = 0.f, ay = 0.f;
    int cnt = 0;
    for (int p = rs + half; p < re; p += 2) {
      int e = ceid[p];
      if (e >= E2) continue;  // skip self-loop rows
      cnt++;
      float2 ea = (e < EE) ? ld2(eattr + (size_t)e * DD + 2 * hl)
                           : make_float2((hl == 0) ? 1.0f : 0.0f, 0.0f);
      ax += ea.x;
      ay += ea.y;
    }
    ax += __shfl_xor(ax, 32);
    ay += __shfl_xor(ay, 32);
    cnt += __shfl_xor(cnt, 32);
    if (half == 0) {
      float inv = 1.0f / fmaxf((float)cnt, 1.0f);
      st2(la + (size_t)i * DD + 2 * hl, ax * inv, ay * inv);
    }
  }
}

// loop_attr for v-nodes is analytically e0 (avg of member e_p rows), or 0 if empty graph
__global__ void la_v_k(const int* __restrict__ gs, float* __restrict__ la) {
  int idx = blockIdx.x * blockDim.x + threadIdx.x;
  if (idx >= GG * DD) return;
  int g = idx >> 6, d = idx & 63;
  float v = (d == 0 && gs[g + 1] > gs[g]) ? 1.0f : 0.0f;
  la[(size_t)(NN + g) * DD + d] = v;
}

// ---------------- LayerNorm (per graph, one pass: sum + sumsq) ----------------

__global__ __launch_bounds__(256) void ln_stats_k(const float* __restrict__ xin,
                                                  const int* __restrict__ gs,
                                                  float* __restrict__ mean,
                                                  float* __restrict__ rstd) {
  __shared__ float red[256], red2[256];
  int g = blockIdx.x;
  int s = gs[g], e = gs[g + 1];
  int cnt = e - s + 1;  // members + graph node
  int nel = cnt * DD;
  float norm = (float)nel;
  float acc = 0.f, acc2 = 0.f;
  for (int idx = threadIdx.x; idx < nel; idx += 256) {
    int loc = idx >> 6;
    int node = (loc < cnt - 1) ? (s + loc) : (NN + g);
    float v = xin[(size_t)node * DD + (idx & 63)];
    acc += v;
    acc2 += v * v;
  }
  red[threadIdx.x] = acc;
  red2[threadIdx.x] = acc2;
  __syncthreads();
  for (int o = 128; o; o >>= 1) {
    if (threadIdx.x < o) {
      red[threadIdx.x] += red[threadIdx.x + o];
      red2[threadIdx.x] += red2[threadIdx.x + o];
    }
    __syncthreads();
  }
  if (threadIdx.x == 0) {
    float mu = red[0] / norm;
    float var = red2[0] / norm - mu * mu;
    mean[g] = mu;
    rstd[g] = rsqrtf(fmaxf(var, 0.f) + EPS_LN_F);
  }
}

__global__ void ln_apply_k(const float* __restrict__ xin, const int* __restrict__ batch,
                           const float* __restrict__ mean, const float* __restrict__ rstd,
                           float* __restrict__ o1, float* __restrict__ o2) {
  for (int idx = blockIdx.x * blockDim.x + threadIdx.x; idx < NAUG * 32;
       idx += gridDim.x * blockDim.x) {
    int i = idx >> 5, d2 = idx & 31;
    int g = (i < NN) ? batch[i] : (i - NN);
    float mu = mean[g], rs = rstd[g];
    float2 v = ld2(xin + (size_t)i * DD + 2 * d2);
    float vx = (v.x - mu) * rs, vy = (v.y - mu) * rs;
    st2(o1 + (size_t)i * DD + 2 * d2, vx, vy);
    if (o2) st2(o2 + (size_t)i * 128 + 2 * d2, vx, vy);  // cat[:, :64]
  }
}

// ---------------- gen_conv aggregation ----------------
// u-nodes: wave per node, 2 edges/iter (one per half)
__global__ __launch_bounds__(256) void gen_u_k(const float* __restrict__ hn,
                                               const int* __restrict__ rowst,
                                               const int* __restrict__ ceid,
                                               const int* __restrict__ csrc,
                                               const float* __restrict__ eattr,
                                               const float* __restrict__ la,
                                               float* __restrict__ gin) {
  const int lane = threadIdx.x & 63;
  const int half = lane >> 5, hl = lane & 31;
  const int wv = threadIdx.x >> 6;
  for (int i = blockIdx.x * 4 + wv; i < NN; i += gridDim.x * 4) {
    int rs = rowst[i], re = rowst[i + 1];
    float ax = 0.f, ay = 0.f;
    for (int p = rs + half; p < re; p += 2) {
      int j = csrc[p], e = ceid[p];
      float2 ea = ea2_val(e, hl, eattr, la);
      float2 hv = ld2(hn + (size_t)j * DD + 2 * hl);
      ax += fmaxf(hv.x + ea.x, 0.f);
      ay += fmaxf(hv.y + ea.y, 0.f);
    }
    ax += __shfl_xor(ax, 32);
    ay += __shfl_xor(ay, 32);
    if (half == 0) {
      float2 hme = ld2(hn + (size_t)i * DD + 2 * hl);
      float epsterm = (float)(re - rs) * EPS_GEN_F;
      st2(gin + (size_t)i * DD + 2 * hl, ax + epsterm + hme.x, ay + epsterm + hme.y);
    }
  }
}

// v-nodes (~392 in-edges): one 512-thread block per node, 16 edge streams
__global__ __launch_bounds__(512) void gen_v_k(const float* __restrict__ hn,
                                               const int* __restrict__ rowst,
                                               const int* __restrict__ ceid,
                                               const int* __restrict__ csrc,
                                               const float* __restrict__ eattr,
                                               const float* __restrict__ la,
                                               float* __restrict__ gin) {
  __shared__ float sacc[8][64];
  const int lane = threadIdx.x & 63;
  const int half = lane >> 5, hl = lane & 31;
  const int wv = threadIdx.x >> 6;  // 0..7
  const int i = NN + blockIdx.x;
  const int rs = rowst[i], re = rowst[i + 1];
  float ax = 0.f, ay = 0.f;
  for (int p = rs + (wv * 2 + half); p < re; p += 16) {
    int j = csrc[p], e = ceid[p];
    float2 ea = ea2_val(e, hl, eattr, la);
    float2 hv = ld2(hn + (size_t)j * DD + 2 * hl);
    ax += fmaxf(hv.x + ea.x, 0.f);
    ay += fmaxf(hv.y + ea.y, 0.f);
  }
  ax += __shfl_xor(ax, 32);
  ay += __shfl_xor(ay, 32);
  if (half == 0) {
    sacc[wv][2 * hl] = ax;
    sacc[wv][2 * hl + 1] = ay;
  }
  __syncthreads();
  if (threadIdx.x < 64) {
    float t = 0.f;
#pragma unroll
    for (int w = 0; w < 8; w++) t += sacc[w][threadIdx.x];
    gin[(size_t)i * DD + threadIdx.x] =
        t + (float)(re - rs) * EPS_GEN_F + hn[(size_t)i * DD + threadIdx.x];
  }
}

// ---------------- GEMM: C[:, coff...] (+)= act(A@W + b) ----------------
// 4 rows per wave iteration; lane owns column pair(s) (ds_read_b64).
// Output column pair cp goes to C[row*ldc + coff + cp*pstride + poff .. +1].
template <int IN, int OUT, int ACT, bool ACCUM>
__global__ __launch_bounds__(256) void gemm_k(const float* __restrict__ A,
                                              const float* __restrict__ W,
                                              const float* __restrict__ bias,
                                              float* __restrict__ C, int ldc, int coff,
                                              int pstride, int poff) {
  __shared__ alignas(16) float sW[IN * OUT];
  for (int idx = threadIdx.x * 4; idx < IN * OUT; idx += 256 * 4)
    *reinterpret_cast<float4*>(&sW[idx]) = *reinterpret_cast<const float4*>(&W[idx]);
  __syncthreads();
  const int lane = threadIdx.x & 63;
  const int wv = threadIdx.x >> 6;
  constexpr int AR = IN / 64;
  constexpr int NP = OUT / 128;  // float2 pairs per lane (OUT==64 -> scalar mode)
  const int gw = blockIdx.x * 4 + wv;
  const int nw = gridDim.x * 4;
  for (int row0 = gw * 4; row0 < NAUG; row0 += nw * 4) {
    float a[4][AR];
#pragma unroll
    for (int rr = 0; rr < 4; rr++)
#pragma unroll
      for (int r = 0; r < AR; r++) a[rr][r] = A[(size_t)(row0 + rr) * IN + r * 64 + lane];
    if constexpr (OUT == 64) {
      float acc[4];
#pragma unroll
      for (int rr = 0; rr < 4; rr++) acc[rr] = bias ? bias[lane] : 0.f;
#pragma unroll
      for (int r = 0; r < AR; r++)
#pragma unroll
        for (int kk = 0; kk < 64; kk++) {
          float w = sW[(r * 64 + kk) * OUT + lane];
#pragma unroll
          for (int rr = 0; rr < 4; rr++) acc[rr] += __shfl(a[rr][r], kk) * w;
        }
#pragma unroll
      for (int rr = 0; rr < 4; rr++) {
        float o = acc[rr];
        if (ACT == 1) o = (o > 0.f) ? o : 0.01f * o;
        float* p = C + (size_t)(row0 + rr) * ldc + coff + lane;
        if (ACCUM)
          *p += o;
        else
          *p = o;
      }
    } else {
      float2 acc[4][NP];
#pragma unroll
      for (int rr = 0; rr < 4; rr++)
#pragma unroll
        for (int pp = 0; pp < NP; pp++)
          acc[rr][pp] = bias ? ld2(bias + 2 * (lane + 64 * pp)) : make_float2(0.f, 0.f);
#pragma unroll
      for (int r = 0; r < AR; r++)
#pragma unroll
        for (int kk = 0; kk < 64; kk++) {
          float2 w[NP];
#pragma unroll
          for (int pp = 0; pp < NP; pp++)
            w[pp] = *reinterpret_cast<const float2*>(
                &sW[(r * 64 + kk) * OUT + 2 * (lane + 64 * pp)]);
#pragma unroll
          for (int rr = 0; rr < 4; rr++) {
            float av = __shfl(a[rr][r], kk);
#pragma unroll
            for (int pp = 0; pp < NP; pp++) {
              acc[rr][pp].x += av * w[pp].x;
              acc[rr][pp].y += av * w[pp].y;
            }
          }
        }
#pragma unroll
      for (int rr = 0; rr < 4; rr++)
#pragma unroll
        for (int pp = 0; pp < NP; pp++) {
          float2 o = acc[rr][pp];
          if (ACT == 1) {
            o.x = (o.x > 0.f) ? o.x : 0.01f * o.x;
            o.y = (o.y > 0.f) ? o.y : 0.01f * o.y;
          }
          float* p = C + (size_t)(row0 + rr) * ldc + coff + (lane + 64 * pp) * pstride + poff;
          if (ACCUM) {
            float2 old = ld2(p);
            st2(p, old.x + o.x, old.y + o.y);
          } else {
            st2(p, o.x, o.y);
          }
        }
    }
  }
}

// Wqe[64h+d][64h+c] = ew[c][64h+d]; zero off-block. (qe = q @ Wqe)
__global__ void wqe_k(const float* __restrict__ ew, float* __restrict__ wqe) {
  int idx = blockIdx.x * 256 + threadIdx.x;
  if (idx >= 128 * 128) return;
  int kcol = idx >> 7, ocol = idx & 127;
  int h = kcol >> 6, c = kcol & 63, h2 = ocol >> 6, d = ocol & 63;
  wqe[idx] = (h == h2) ? ew[d * 128 + 64 * h + c] : 0.f;
}

// block-diag weight: Wbd[64h+c][64h+d] = ew[c][64h+d]
__global__ void wbd_k(const float* __restrict__ ew, float* __restrict__ wbd) {
  int idx = blockIdx.x * 256 + threadIdx.x;
  if (idx >= 128 * 128) return;
  int k = idx >> 7, o = idx & 127;
  wbd[idx] = ((k >> 6) == (o >> 6)) ? ew[(k & 63) * 128 + o] : 0.f;
}

// ---------------- attention: single-pass online softmax ----------------
// kv layout: kv[node][4p..4p+3] = {k[2p],k[2p+1],v[2p],v[2p+1]} -> one dwordx4/edge/lane.
// Lane owns features {2l,2l+1}; head 0 = lanes 0..31, head 1 = lanes 32..63.
__global__ __launch_bounds__(256) void attn_u_k(
    const float* __restrict__ q, const float* __restrict__ kv, const float* __restrict__ qe,
    const int* __restrict__ rowst, const int* __restrict__ ceid, const int* __restrict__ csrc,
    const float* __restrict__ eattr, const float* __restrict__ la, float* __restrict__ outv,
    float* __restrict__ z) {
  const int lane = threadIdx.x & 63;
  const int hl = lane & 31;
  const int wv = threadIdx.x >> 6;
  for (int i = blockIdx.x * 4 + wv; i < NN; i += gridDim.x * 4) {
    const int rs = rowst[i], re = rowst[i + 1];
    float2 q2 = ld2(q + (size_t)i * 128 + 2 * lane);
    float2 e2 = ld2(qe + (size_t)i * 128 + 2 * lane);
    float m = -1e30f, s = 0.f;
    float avx = 0.f, avy = 0.f, azx = 0.f, azy = 0.f;
    for (int p = rs; p < re; ++p) {
      int j = csrc[p], e = ceid[p];
      float2 ea = ea2_val(e, hl, eattr, la);
      float4 kv4 = ld4(kv + (size_t)j * 256 + 4 * lane);
      float part = q2.x * kv4.x + q2.y * kv4.y + e2.x * ea.x + e2.y * ea.y;
      float a = half_sum(part) * 0.125f;
      float nm = fmaxf(m, a);
      float c = __expf(m - nm), w = __expf(a - nm);
      m = nm;
      s = s * c + w;
      avx = avx * c + w * kv4.z;
      avy = avy * c + w * kv4.w;
      azx = azx * c + w * ea.x;
      azy = azy * c + w * ea.y;
    }
    float inv = 1.0f / (s + 1e-16f);
    st2(outv + (size_t)i * 128 + 2 * lane, avx * inv, avy * inv);
    st2(z + (size_t)i * 128 + 2 * lane, azx * inv, azy * inv);
  }
}

// v-nodes: one 512-thread block per node; 8 per-wave online states merged in LDS
__global__ __launch_bounds__(512) void attn_v_k(
    const float* __restrict__ q, const float* __restrict__ kv, const float* __restrict__ qe,
    const int* __restrict__ rowst, const int* __restrict__ ceid, const int* __restrict__ csrc,
    const float* __restrict__ eattr, const float* __restrict__ la, float* __restrict__ outv,
    float* __restrict__ z) {
  __shared__ float sm[8][2], ss[8][2], sav[8][128], saz[8][128];
  const int lane = threadIdx.x & 63;
  const int hl = lane & 31;
  const int wv = threadIdx.x >> 6;  // 0..7
  const int i = NN + blockIdx.x;
  const int rs = rowst[i], re = rowst[i + 1];
  float2 q2 = ld2(q + (size_t)i * 128 + 2 * lane);
  float2 e2 = ld2(qe + (size_t)i * 128 + 2 * lane);
  float m = -1e30f, s = 0.f;
  float avx = 0.f, avy = 0.f, azx = 0.f, azy = 0.f;
  for (int p = rs + wv; p < re; p += 8) {
    int j = csrc[p], e = ceid[p];
    float2 ea = ea2_val(e, hl, eattr, la);
    float4 kv4 = ld4(kv + (size_t)j * 256 + 4 * lane);
    float part = q2.x * kv4.x + q2.y * kv4.y + e2.x * ea.x + e2.y * ea.y;
    float a = half_sum(part) * 0.125f;
    float nm = fmaxf(m, a);
    float c = __expf(m - nm), w = __expf(a - nm);
    m = nm;
    s = s * c + w;
    avx = avx * c + w * kv4.z;
    avy = avy * c + w * kv4.w;
    azx = azx * c + w * ea.x;
    azy = azy * c + w * ea.y;
  }
  if (hl == 0) {
    sm[wv][lane >> 5] = m;
    ss[wv][lane >> 5] = s;
  }
  sav[wv][2 * lane] = avx;
  sav[wv][2 * lane + 1] = avy;
  saz[wv][2 * lane] = azx;
  saz[wv][2 * lane + 1] = azy;
  __syncthreads();
  if (wv == 0) {
    int half = lane >> 5;
    float M = -1e30f;
#pragma unroll
    for (int w = 0; w < 8; w++) M = fmaxf(M, sm[w][half]);
    float stot = 0.f, AVX = 0.f, AVY = 0.f, AZX = 0.f, AZY = 0.f;
#pragma unroll
    for (int w = 0; w < 8; w++) {
      float sc = __expf(sm[w][half] - M);
      stot += ss[w][half] * sc;
      AVX += sav[w][2 * lane] * sc;
      AVY += sav[w][2 * lane + 1] * sc;
      AZX += saz[w][2 * lane] * sc;
      AZY += saz[w][2 * lane + 1] * sc;
    }
    float inv = 1.0f / (stot + 1e-16f);
    st2(outv + (size_t)i * 128 + 2 * lane, AVX * inv, AVY * inv);
    st2(z + (size_t)i * 128 + 2 * lane, AZX * inv, AZY * inv);
  }
}

// ---------------- outputs ----------------

__global__ void nemb_k(const float4* __restrict__ h, float4* __restrict__ out) {
  for (int idx = blockIdx.x * blockDim.x + threadIdx.x; idx < NN * 16;
       idx += gridDim.x * blockDim.x)
    out[idx] = h[idx];
}

__global__ __launch_bounds__(256) void glob_k(const float* __restrict__ h,
                                              const int* __restrict__ gs,
                                              float* __restrict__ out) {
  __shared__ float part[4][64];
  int g = blockIdx.x;
  int d = threadIdx.x & 63, sub = threadIdx.x >> 6;
  int s = gs[g], e = gs[g + 1];
  float acc = 0.f;
  for (int node = s + sub; node < e; node += 4) acc += h[(size_t)node * DD + d];
  part[sub][d] = acc;
  __syncthreads();
  if (sub == 0) {
    float t = part[0][d] + part[1][d] + part[2][d] + part[3][d];
    t /= fmaxf((float)(e - s), 1.0f);
    t += h[(size_t)(NN + g) * DD + d];
    out[(size_t)NN * DD + (size_t)g * DD + d] = t;
  }
}

__global__ void ne_k(const float4* __restrict__ h4, const int* __restrict__ a,
                     const int* __restrict__ b, float4* __restrict__ out4) {
  const size_t base = (size_t)(NN + GG) * 16;
  for (size_t idx = blockIdx.x * blockDim.x + threadIdx.x; idx < (size_t)NEE * 16;
       idx += (size_t)gridDim.x * blockDim.x) {
    int r = (int)(idx >> 4), c = (int)(idx & 15);
    float4 va = h4[(size_t)a[r] * 16 + c];
    float4 vb = h4[(size_t)b[r] * 16 + c];
    out4[base + idx] = make_float4(va.x + vb.x, va.y + vb.y, va.z + vb.z, va.w + vb.w);
  }
}

// ---------------- host ----------------

extern "C" void kernel_launch(void* const* d_in, const int* in_sizes, int n_in, void* d_out,
                              int out_size, void* d_ws, size_t ws_size, hipStream_t stream) {
  const float* x = (const float*)d_in[0];
  const float* cond = (const float*)d_in[1];
  const float* eattr = (const float*)d_in[2];
  const int* eidx = (const int*)d_in[3];
  const int* neidx = (const int*)d_in[4];
  const int* batch = (const int*)d_in[5];
  const float* gen_w = (const float*)d_in[6];
  const float* gen_b = (const float*)d_in[7];
  const float* q_w = (const float*)d_in[8];
  const float* q_b = (const float*)d_in[9];
  const float* k_w = (const float*)d_in[10];
  const float* k_b = (const float*)d_in[11];
  const float* v_w = (const float*)d_in[12];
  const float* v_b = (const float*)d_in[13];
  const float* e_w = (const float*)d_in[14];
  const float* skip_w = (const float*)d_in[15];
  const float* skip_b = (const float*)d_in[16];
  const float* lin_w = (const float*)d_in[17];
  const float* lin_b = (const float*)d_in[18];
  const float* ff_w1 = (const float*)d_in[19];
  const float* ff_b1 = (const float*)d_in[20];
  const float* ff_w2 = (const float*)d_in[21];
  const float* ff_b2 = (const float*)d_in[22];
  float* out = (float*)d_out;

  size_t off = 0;
  auto alloc = [&](size_t bytes) -> void* {
    void* p = (char*)d_ws + off;
    off += (bytes + 255) & ~(size_t)255;
    return p;
  };
  float* h = (float*)alloc((size_t)NAUG * 64 * 4);
  float* la = (float*)alloc((size_t)NAUG * 64 * 4);
  float* hn = (float*)alloc((size_t)NAUG * 64 * 4);
  float* cat = (float*)alloc((size_t)NAUG * 128 * 4);
  float* qb_ = (float*)alloc((size_t)NAUG * 128 * 4);   // q; later ln2
  float* qeb = (float*)alloc((size_t)NAUG * 128 * 4);   // qe
  float* kvb = (float*)alloc((size_t)NAUG * 256 * 4);   // interleaved k|v; later ffmid
  float* ob = (float*)alloc((size_t)NAUG * 128 * 4);    // attn out (+skip +z@ew)
  float* zb = (float*)alloc((size_t)NAUG * 128 * 4);    // gen agg, then attn z
  int* deg = (int*)alloc((size_t)NAUG * 4);
  int* fill = (int*)alloc((size_t)NAUG * 4);
  int* rowst = (int*)alloc((size_t)(NAUG + 1) * 4);
  int* ceid = (int*)alloc((size_t)ESZ * 4);
  int* csrc = (int*)alloc((size_t)ESZ * 4);
  int* gs = (int*)alloc((size_t)(GG + 1) * 4);
  int* bsum = (int*)alloc((size_t)NBLK * 4);
  int* bpre = (int*)alloc((size_t)(NBLK + 1) * 4);
  float* mean = (float*)alloc(GG * 4);
  float* rstd = (float*)alloc(GG * 4);
  float* wbd = (float*)alloc(128 * 128 * 4);
  float* wqe = (float*)alloc(128 * 128 * 4);
  (void)ws_size;

  // ---- graph preprocessing ----
  hipMemsetAsync(deg, 0, (size_t)NAUG * 4, stream);
  hist_k<<<1024, 256, 0, stream>>>(eidx + EE, batch, deg);
  scan1_k<<<NBLK, SCAN_B, 0, stream>>>(deg, rowst, bsum);
  scan2_k<<<1, 64, 0, stream>>>(bsum, bpre, rowst);
  scan3_k<<<(NAUG + 255) / 256, 256, 0, stream>>>(rowst, bpre);
  hipMemsetAsync(fill, 0, (size_t)NAUG * 4, stream);
  scatter_k<<<1024, 256, 0, stream>>>(eidx, eidx + EE, batch, rowst, fill, ceid, csrc);
  gs_k<<<(NN + 255) / 256, 256, 0, stream>>>(batch, gs);
  hinit_k<<<2048, 256, 0, stream>>>((const float4*)x, (const float4*)cond, (float4*)h);
  loopattr_u_k<<<2048, 256, 0, stream>>>(eattr, rowst, ceid, la);
  la_v_k<<<32, 256, 0, stream>>>(gs, la);

  for (int l = 0; l < LAY; l++) {
    const float* gw = gen_w + (size_t)l * 64 * 64;
    const float* gb = gen_b + (size_t)l * 64;
    const float* qw = q_w + (size_t)l * 128 * 128;
    const float* qbia = q_b + (size_t)l * 128;
    const float* kw = k_w + (size_t)l * 128 * 128;
    const float* kbia = k_b + (size_t)l * 128;
    const float* vw = v_w + (size_t)l * 128 * 128;
    const float* vbia = v_b + (size_t)l * 128;
    const float* ew = e_w + (size_t)l * 64 * 128;
    const float* sw = skip_w + (size_t)l * 128 * 128;
    const float* sb = skip_b + (size_t)l * 128;
    const float* lw = lin_w + (size_t)l * 128 * 64;
    const float* lb = lin_b + (size_t)l * 64;
    const float* f1w = ff_w1 + (size_t)l * 64 * 256;
    const float* f1b = ff_b1 + (size_t)l * 256;
    const float* f2w = ff_w2 + (size_t)l * 256 * 64;
    const float* f2b = ff_b2 + (size_t)l * 64;

    ln_stats_k<<<GG, 256, 0, stream>>>(h, gs, mean, rstd);
    ln_apply_k<<<2048, 256, 0, stream>>>(h, batch, mean, rstd, hn, cat);  // hn + cat[:,:64]
    gen_u_k<<<2048, 256, 0, stream>>>(hn, rowst, ceid, csrc, eattr, la, zb);
    gen_v_k<<<GG, 512, 0, stream>>>(hn, rowst, ceid, csrc, eattr, la, zb);
    gemm_k<64, 64, 0, false><<<1024, 256, 0, stream>>>(zb, gw, gb, cat, 128, 64, 2, 0);
    gemm_k<128, 128, 0, false><<<1024, 256, 0, stream>>>(cat, qw, qbia, qb_, 128, 0, 2, 0);
    wqe_k<<<64, 256, 0, stream>>>(ew, wqe);
    gemm_k<128, 128, 0, false><<<1024, 256, 0, stream>>>(qb_, wqe, nullptr, qeb, 128, 0, 2, 0);
    gemm_k<128, 128, 0, false><<<1024, 256, 0, stream>>>(cat, kw, kbia, kvb, 256, 0, 4, 0);
    gemm_k<128, 128, 0, false><<<1024, 256, 0, stream>>>(cat, vw, vbia, kvb, 256, 0, 4, 2);
    attn_u_k<<<2048, 256, 0, stream>>>(qb_, kvb, qeb, rowst, ceid, csrc, eattr, la, ob, zb);
    attn_v_k<<<GG, 512, 0, stream>>>(qb_, kvb, qeb, rowst, ceid, csrc, eattr, la, ob, zb);
    wbd_k<<<64, 256, 0, stream>>>(ew, wbd);
    gemm_k<128, 128, 0, true><<<1024, 256, 0, stream>>>(cat, sw, sb, ob, 128, 0, 2, 0);
    gemm_k<128, 128, 0, true><<<1024, 256, 0, stream>>>(zb, wbd, nullptr, ob, 128, 0, 2, 0);
    gemm_k<128, 64, 0, false><<<1024, 256, 0, stream>>>(ob, lw, lb, hn, 64, 0, 2, 0);
    ln_stats_k<<<GG, 256, 0, stream>>>(hn, gs, mean, rstd);
    ln_apply_k<<<2048, 256, 0, stream>>>(hn, batch, mean, rstd, qb_, nullptr);  // ln2 -> qb_
    gemm_k<64, 256, 1, false><<<1024, 256, 0, stream>>>(qb_, f1w, f1b, kvb, 256, 0, 2, 0);
    gemm_k<256, 64, 0, true><<<1024, 256, 0, stream>>>(kvb, f2w, f2b, h, 64, 0, 2, 0);
  }

  nemb_k<<<2048, 256, 0, stream>>>((const float4*)h, (float4*)out);
  glob_k<<<GG, 256, 0, stream>>>(h, gs, out);
  ne_k<<<8192, 256, 0, stream>>>((const float4*)h, neidx, neidx + NEE, (float4*)out);
}